// Round 9
// baseline (251.252 us; speedup 1.0000x reference)
//
#include <hip/hip_runtime.h>

#define SDIM 2048
#define DDIM 1024
#define NH 16
#define DK 64
#define NB 2
#define MROWS (NB * SDIM) // 4096
#define MAXEV 65536
#define EXPC 0.18033688011112f // 0.125 * log2(e), folded into Q at projection
#define L01 -3.3219281f        // log2(0.1)

typedef _Float16 f16x8 __attribute__((ext_vector_type(8)));
typedef _Float16 f16x4 __attribute__((ext_vector_type(4)));
typedef float f32x4 __attribute__((ext_vector_type(4)));

__device__ __forceinline__ void ld_lds16(const _Float16* g, _Float16* l) {
  __builtin_amdgcn_global_load_lds(
      (const __attribute__((address_space(1))) void*)g,
      (__attribute__((address_space(3))) void*)l, 16, 0, 0);
}

// ---------- K0: fp32 -> fp16 convert (x, Wq, Wk; V path needs no fp16) ----------
__global__ __launch_bounds__(256) void cvt_f16(
    const float* __restrict__ x, const float* __restrict__ wq,
    const float* __restrict__ wk, _Float16* __restrict__ xh,
    _Float16* __restrict__ wqh, _Float16* __restrict__ wkh) {
  int i = blockIdx.x * 256 + threadIdx.x; // float4 index
  const float* src;
  _Float16* dst;
  int off;
  if (i < 1048576) {
    src = x; dst = xh; off = i;
  } else if (i < 1310720) {
    src = wq; dst = wqh; off = i - 1048576;
  } else {
    src = wk; dst = wkh; off = i - 1310720;
  }
  float4 v = ((const float4*)src)[off];
  f16x4 h;
  h[0] = (_Float16)v.x; h[1] = (_Float16)v.y;
  h[2] = (_Float16)v.z; h[3] = (_Float16)v.w;
  ((f16x4*)dst)[off] = h;
}

// ---------- K1: fused QK projection, fp16 MFMA, 128x128 tile, BK=64.
// Q output pre-scaled by EXPC so scores exit MFMA as exp2 arguments. ----------
__global__ __launch_bounds__(256, 2) void proj_gemm(
    const _Float16* __restrict__ xh, const _Float16* __restrict__ Wqh,
    const _Float16* __restrict__ Wkh, const float* __restrict__ bq,
    const float* __restrict__ bk, _Float16* __restrict__ Qo,
    _Float16* __restrict__ Ko) {
  __shared__ _Float16 sA[128 * 64]; // 16KB, XOR-swizzled chunks
  __shared__ _Float16 sB[128 * 64];
  const int t = threadIdx.x;
  const int lane = t & 63, wv = t >> 6;
  const int lr = lane & 15, quad = lane >> 4;
  const int wm = wv >> 1, wn = wv & 1;
  const int m0 = blockIdx.y * 128, n0 = blockIdx.x * 128;
  const int z = blockIdx.z;
  const _Float16* Bp = z == 0 ? Wqh : Wkh;
  const float* bias = z == 0 ? bq : bk;

  const int strow = t >> 3;
  const int stchunk = t & 7;
  const int stsrc = (stchunk ^ (strow & 7)) * 8;

  f32x4 acc[4][4];
#pragma unroll
  for (int i = 0; i < 4; ++i)
#pragma unroll
    for (int j = 0; j < 4; ++j) acc[i][j] = (f32x4){0.f, 0.f, 0.f, 0.f};

  for (int k0 = 0; k0 < DDIM; k0 += 64) {
    __syncthreads();
#pragma unroll
    for (int i = 0; i < 4; ++i) {
      const int row = i * 32 + strow;
      ld_lds16(&xh[(size_t)(m0 + row) * DDIM + k0 + stsrc],
               &sA[row * 64 + stchunk * 8]);
      ld_lds16(&Bp[(size_t)(n0 + row) * DDIM + k0 + stsrc],
               &sB[row * 64 + stchunk * 8]);
    }
    __syncthreads();
    f16x8 af[4][2], bf[4][2];
#pragma unroll
    for (int i = 0; i < 4; ++i)
#pragma unroll
      for (int kk = 0; kk < 2; ++kk) {
        const int ph = ((kk * 4 + quad) ^ (lr & 7)) * 8;
        af[i][kk] = *(const f16x8*)&sA[(wm * 64 + i * 16 + lr) * 64 + ph];
        bf[i][kk] = *(const f16x8*)&sB[(wn * 64 + i * 16 + lr) * 64 + ph];
      }
#pragma unroll
    for (int kk = 0; kk < 2; ++kk)
#pragma unroll
      for (int i = 0; i < 4; ++i)
#pragma unroll
        for (int j = 0; j < 4; ++j)
          acc[i][j] = __builtin_amdgcn_mfma_f32_16x16x32_f16(
              af[i][kk], bf[j][kk], acc[i][j], 0, 0, 0);
  }
#pragma unroll
  for (int j = 0; j < 4; ++j) {
    const int ng = n0 + wn * 64 + j * 16 + lr;
    const float bvv = bias[ng];
    const int h = ng >> 6, d = ng & 63;
#pragma unroll
    for (int i = 0; i < 4; ++i) {
#pragma unroll
      for (int r = 0; r < 4; ++r) {
        const int mg = m0 + wm * 64 + i * 16 + quad * 4 + r;
        const int b = mg >> 11, s = mg & 2047;
        const float o = acc[i][j][r] + bvv;
        const size_t off = ((size_t)(b * NH + h) * SDIM + s) * DK + d;
        if (z == 0)
          Qo[off] = (_Float16)(o * EXPC); // pre-scaled Q
        else
          Ko[off] = (_Float16)o;
      }
    }
  }
}

// ---------- K2: den += sum_k 2^(Q'.K) partials. Grid (q0, bh, ksplit=2);
// each wave owns 32 of the 128 staged K-rows (LDS reads /4); A-frags for all
// 64 q-rows loaded once; float atomicAdd partials into den. ----------
__global__ __launch_bounds__(256) void attn_denom(const _Float16* __restrict__ Q,
                                                  const _Float16* __restrict__ K,
                                                  float* __restrict__ den) {
  __shared__ _Float16 Ks[128 * 64]; // 16KB
  const int t = threadIdx.x;
  const int lane = t & 63, wave = t >> 6;
  const int quad = lane >> 4, lr = lane & 15;
  const int q0 = blockIdx.x * 64;
  const int bh = blockIdx.y;
  const int ks = blockIdx.z;
  const _Float16* Qh = Q + (size_t)bh * SDIM * DK;
  const _Float16* Kh = K + (size_t)bh * SDIM * DK + (size_t)ks * 1024 * DK;
  const int strow = t >> 3, stchunk = t & 7;
  const int stsrc = (stchunk ^ (strow & 7)) * 8;
  const int ph0 = (quad ^ (lr & 7)) * 8;
  const int ph1 = ((4 + quad) ^ (lr & 7)) * 8;

  f16x8 aq[4][2];
#pragma unroll
  for (int m = 0; m < 4; ++m) {
    const size_t qo = (size_t)(q0 + m * 16 + lr) * DK + quad * 8;
    aq[m][0] = *(const f16x8*)&Qh[qo];
    aq[m][1] = *(const f16x8*)&Qh[qo + 32];
  }

  float dsum[4][4] = {};
#pragma unroll 1
  for (int kt = 0; kt < 8; ++kt) {
    __syncthreads(); // prior stage's reads done
#pragma unroll
    for (int i = 0; i < 4; ++i)
      ld_lds16(&Kh[(size_t)(kt * 128 + i * 32 + strow) * DK + stsrc],
               &Ks[(i * 32 + strow) * 64 + stchunk * 8]);
    __syncthreads(); // DMA drained
#pragma unroll
    for (int cc = 0; cc < 2; ++cc) {
      const int c = wave * 2 + cc; // this wave's 32-row strip
      f16x8 b0 = *(const f16x8*)&Ks[(c * 16 + lr) * 64 + ph0];
      f16x8 b1 = *(const f16x8*)&Ks[(c * 16 + lr) * 64 + ph1];
#pragma unroll
      for (int m = 0; m < 4; ++m) {
        f32x4 acc = {0.f, 0.f, 0.f, 0.f};
        acc = __builtin_amdgcn_mfma_f32_16x16x32_f16(aq[m][0], b0, acc, 0, 0, 0);
        acc = __builtin_amdgcn_mfma_f32_16x16x32_f16(aq[m][1], b1, acc, 0, 0, 0);
#pragma unroll
        for (int r = 0; r < 4; ++r)
          dsum[m][r] += __builtin_amdgcn_exp2f(acc[r]);
      }
    }
  }
#pragma unroll
  for (int mk = 1; mk < 16; mk <<= 1)
#pragma unroll
    for (int m = 0; m < 4; ++m)
#pragma unroll
      for (int r = 0; r < 4; ++r)
        dsum[m][r] += __shfl_xor(dsum[m][r], mk, 64);
  if (lr == 0) {
#pragma unroll
    for (int m = 0; m < 4; ++m)
#pragma unroll
      for (int r = 0; r < 4; ++r)
        atomicAdd(&den[(size_t)bh * SDIM + q0 + m * 16 + quad * 4 + r],
                  dsum[m][r]);
  }
}

// ---------- K3: att_sum dense. Waves {0,1} own even head of each stage
// (q-rows 0-31 / 32-63), waves {2,3} the odd head -> LDS reads /2.
// la = -log2(den) computed inline. attMask pre-zeroed by memset; cold path
// (never taken) atomicAdds nonzeros + events. ----------
__global__ __launch_bounds__(256) void attn_pass2(
    const _Float16* __restrict__ Q, const _Float16* __restrict__ K,
    const float* __restrict__ den, float* __restrict__ attSum,
    float* __restrict__ attMask, float4* __restrict__ ev,
    int* __restrict__ ecnt) {
  __shared__ float SMEM[64 * 68]; // 17.4KB; first 16KB = 2-head K stage
  _Float16* Khs = (_Float16*)SMEM;
  float* Tbuf = SMEM;
  const int t = threadIdx.x;
  const int lane = t & 63, wave = t >> 6;
  const int quad = lane >> 4, lr = lane & 15;
  const int par = wave >> 1; // 0: even head, 1: odd head of the stage
  const int p = wave & 1;    // q-row half: rows p*32..p*32+31
  const int k0 = blockIdx.x * 64;
  const int q0 = blockIdx.y * 64;
  const int b = blockIdx.z;
  const int strow = t >> 3, stchunk = t & 7;
  const int stsrc = (stchunk ^ (strow & 7)) * 8;
  const int ph0 = (quad ^ (lr & 7)) * 8;
  const int ph1 = ((4 + quad) ^ (lr & 7)) * 8;

  const size_t hstep = (size_t)SDIM * DK;
  // this wave's Q-row base (per m-tile): q0 + p*32 + m*16 + lr
  const size_t qrow0 = (size_t)(b * NH) * SDIM + q0 + p * 32;

  float asum[2][4][4] = {};
  float mx = -1e30f;

#pragma unroll 1
  for (int hp = 0; hp < 8; ++hp) {
    __syncthreads(); // prior stage's LDS reads done
#pragma unroll
    for (int hh = 0; hh < 2; ++hh) {
      const _Float16* Kp =
          K + (size_t)(b * NH + 2 * hp + hh) * hstep + (size_t)k0 * DK;
#pragma unroll
      for (int i = 0; i < 2; ++i)
        ld_lds16(&Kp[(size_t)(i * 32 + strow) * DK + stsrc],
                 &Khs[hh * 4096 + (i * 32 + strow) * 64 + stchunk * 8]);
    }
    const int h = 2 * hp + par; // this wave's head
    f16x8 aq[2][2];
    float4 dn[2];
#pragma unroll
    for (int m = 0; m < 2; ++m) {
      const size_t qo = (qrow0 + (size_t)h * SDIM + m * 16 + lr) * DK + quad * 8;
      aq[m][0] = *(const f16x8*)&Q[qo];
      aq[m][1] = *(const f16x8*)&Q[qo + 32];
      dn[m] = *(const float4*)&den[qrow0 + (size_t)h * SDIM + m * 16 + quad * 4];
    }
    __syncthreads(); // DMA + loads landed
    float lar[2][4];
#pragma unroll
    for (int m = 0; m < 2; ++m) {
      lar[m][0] = -__builtin_amdgcn_logf(dn[m].x);
      lar[m][1] = -__builtin_amdgcn_logf(dn[m].y);
      lar[m][2] = -__builtin_amdgcn_logf(dn[m].z);
      lar[m][3] = -__builtin_amdgcn_logf(dn[m].w);
    }
    const _Float16* Ks = &Khs[par * 4096];
#pragma unroll
    for (int c = 0; c < 4; ++c) {
      f16x8 b0 = *(const f16x8*)&Ks[(c * 16 + lr) * 64 + ph0];
      f16x8 b1 = *(const f16x8*)&Ks[(c * 16 + lr) * 64 + ph1];
#pragma unroll
      for (int m = 0; m < 2; ++m) {
        f32x4 acc = {0.f, 0.f, 0.f, 0.f};
        acc = __builtin_amdgcn_mfma_f32_16x16x32_f16(aq[m][0], b0, acc, 0, 0, 0);
        acc = __builtin_amdgcn_mfma_f32_16x16x32_f16(aq[m][1], b1, acc, 0, 0, 0);
#pragma unroll
        for (int r = 0; r < 4; ++r) {
          const float arg = acc[r] + lar[m][r];
          mx = fmaxf(mx, arg);
          asum[m][c][r] += __builtin_amdgcn_exp2f(arg);
        }
      }
    }
  }
  if (__any(mx >= L01)) { // cold: recompute this wave's subset, direct loads
#pragma unroll 1
    for (int h = par; h < NH; h += 2) {
      const _Float16* Kp =
          K + (size_t)(b * NH + h) * hstep + (size_t)k0 * DK;
      f16x8 aq[2][2];
      float lar[2][4];
#pragma unroll 1
      for (int m = 0; m < 2; ++m) {
        const size_t qo =
            (qrow0 + (size_t)h * SDIM + m * 16 + lr) * DK + quad * 8;
        aq[m][0] = *(const f16x8*)&Q[qo];
        aq[m][1] = *(const f16x8*)&Q[qo + 32];
        const float4 dn =
            *(const float4*)&den[qrow0 + (size_t)h * SDIM + m * 16 + quad * 4];
        lar[m][0] = -__builtin_amdgcn_logf(dn.x);
        lar[m][1] = -__builtin_amdgcn_logf(dn.y);
        lar[m][2] = -__builtin_amdgcn_logf(dn.z);
        lar[m][3] = -__builtin_amdgcn_logf(dn.w);
      }
#pragma unroll 1
      for (int c = 0; c < 4; ++c) {
        const f16x8 b0 = *(const f16x8*)&Kp[(c * 16 + lr) * DK + quad * 8];
        const f16x8 b1 = *(const f16x8*)&Kp[(c * 16 + lr) * DK + 32 + quad * 8];
#pragma unroll 1
        for (int m = 0; m < 2; ++m) {
          f32x4 acc = {0.f, 0.f, 0.f, 0.f};
          acc = __builtin_amdgcn_mfma_f32_16x16x32_f16(aq[m][0], b0, acc, 0, 0, 0);
          acc = __builtin_amdgcn_mfma_f32_16x16x32_f16(aq[m][1], b1, acc, 0, 0, 0);
#pragma unroll 1
          for (int r = 0; r < 4; ++r) {
            const float pv = __builtin_amdgcn_exp2f(acc[r] + lar[m][r]);
            if (pv >= 0.1f) {
              const int qrow = q0 + p * 32 + m * 16 + quad * 4 + r;
              const int kcol = k0 + c * 16 + lr;
              atomicAdd(&attMask[((size_t)(b * SDIM) + qrow) * SDIM + kcol],
                        1.0f);
              int idx = atomicAdd(ecnt, 1);
              if (idx < MAXEV)
                ev[idx] = make_float4(__int_as_float(b * NH + h),
                                      __int_as_float(qrow),
                                      __int_as_float(kcol), pv);
            }
          }
        }
      }
    }
  }
  // epilogue: pairwise cross-wave reduce + transpose -> coalesced stores
  __syncthreads();
  if (wave < 2) {
#pragma unroll
    for (int m = 0; m < 2; ++m)
#pragma unroll
      for (int c = 0; c < 4; ++c)
#pragma unroll
        for (int r = 0; r < 4; ++r)
          Tbuf[(p * 32 + m * 16 + quad * 4 + r) * 68 + c * 16 + lr] =
              asum[m][c][r];
  }
  __syncthreads();
  if (wave >= 2) {
#pragma unroll
    for (int m = 0; m < 2; ++m)
#pragma unroll
      for (int c = 0; c < 4; ++c)
#pragma unroll
        for (int r = 0; r < 4; ++r) {
          const int a = (p * 32 + m * 16 + quad * 4 + r) * 68 + c * 16 + lr;
          Tbuf[a] += asum[m][c][r];
        }
  }
  __syncthreads();
  const int orow = t >> 2, ocol = (t & 3) * 16;
#pragma unroll
  for (int j = 0; j < 4; ++j) {
    float4 v = *(float4*)&Tbuf[orow * 68 + ocol + j * 4];
    *(float4*)&attSum[((size_t)(b * SDIM) + q0 + orow) * SDIM + k0 + ocol +
                      j * 4] = v;
  }
}

// ---------- K3b: apply rare events; V row computed on the fly (fp32) ----------
__global__ __launch_bounds__(64) void apply_events(
    const float4* __restrict__ ev, const int* __restrict__ ecnt,
    const float* __restrict__ x, const float* __restrict__ Wv,
    const float* __restrict__ bv, float* __restrict__ merged,
    int* __restrict__ flags) {
  int n = *ecnt;
  if (n > MAXEV) n = MAXEV;
  const int d = threadIdx.x;
  for (int e = blockIdx.x; e < n; e += gridDim.x) {
    float4 r = ev[e];
    int bh = __float_as_int(r.x);
    int q = __float_as_int(r.y);
    int kc = __float_as_int(r.z);
    float pv = r.w;
    int b = bh >> 4, h = bh & 15;
    float acc = bv[h * DK + d];
    const float* xr = &x[((size_t)(b * SDIM) + kc) * DDIM];
    const float* wr = &Wv[(size_t)(h * DK + d) * DDIM];
    for (int j = 0; j < DDIM; ++j) acc = fmaf(xr[j], wr[j], acc);
    atomicAdd(&merged[((size_t)(b * SDIM + q)) * DDIM + h * DK + d], pv * acc);
    if (d == 0) flags[b * SDIM + q] = 1;
  }
}

// ---------- K4: output projection with all-zero-row-tile skip ----------
__global__ __launch_bounds__(256) void out_gemm(const float* __restrict__ A,
                                                const float* __restrict__ W,
                                                const float* __restrict__ bias,
                                                float* __restrict__ out,
                                                const int* __restrict__ flags) {
  __shared__ float As[16][68];
  __shared__ float Ws[16][68];
  __shared__ int anyF;
  const int t = threadIdx.x;
  const int tx = t & 15, ty = t >> 4;
  const int m0 = blockIdx.y * 64;
  const int n0 = blockIdx.x * 64;
  if (t == 0) anyF = 0;
  __syncthreads();
  if (t < 64 && flags[m0 + t]) anyF = 1;
  __syncthreads();
  const int nb = n0 + tx * 4;
  const float4 bv = *(const float4*)&bias[nb];
  if (!anyF) {
#pragma unroll
    for (int r = 0; r < 4; ++r)
      *(float4*)&out[(size_t)(m0 + ty * 4 + r) * DDIM + nb] = bv;
    return;
  }
  const int lr = t >> 2;
  const int lc = (t & 3) * 4;
  float acc[4][4] = {};
  for (int k0 = 0; k0 < DDIM; k0 += 16) {
    __syncthreads();
    float4 av = *(const float4*)&A[(size_t)(m0 + lr) * DDIM + k0 + lc];
    float4 wv = *(const float4*)&W[(size_t)(n0 + lr) * DDIM + k0 + lc];
    As[lc + 0][lr] = av.x; As[lc + 1][lr] = av.y;
    As[lc + 2][lr] = av.z; As[lc + 3][lr] = av.w;
    Ws[lc + 0][lr] = wv.x; Ws[lc + 1][lr] = wv.y;
    Ws[lc + 2][lr] = wv.z; Ws[lc + 3][lr] = wv.w;
    __syncthreads();
#pragma unroll
    for (int kk = 0; kk < 16; ++kk) {
      float4 a4 = *(const float4*)&As[kk][ty * 4];
      float4 b4 = *(const float4*)&Ws[kk][tx * 4];
      const float a[4] = {a4.x, a4.y, a4.z, a4.w};
      const float b[4] = {b4.x, b4.y, b4.z, b4.w};
#pragma unroll
      for (int r = 0; r < 4; ++r)
#pragma unroll
        for (int c = 0; c < 4; ++c)
          acc[r][c] = fmaf(a[r], b[c], acc[r][c]);
    }
  }
#pragma unroll
  for (int r = 0; r < 4; ++r) {
    float4 o;
    o.x = acc[r][0] + bv.x;
    o.y = acc[r][1] + bv.y;
    o.z = acc[r][2] + bv.z;
    o.w = acc[r][3] + bv.w;
    *(float4*)&out[(size_t)(m0 + ty * 4 + r) * DDIM + nb] = o;
  }
}

// ---------- launcher ----------
extern "C" void kernel_launch(void* const* d_in, const int* in_sizes, int n_in,
                              void* d_out, int out_size, void* d_ws,
                              size_t ws_size, hipStream_t stream) {
  const float* x = (const float*)d_in[0];
  const float* Wq = (const float*)d_in[1];
  const float* bq = (const float*)d_in[2];
  const float* Wk = (const float*)d_in[3];
  const float* bk = (const float*)d_in[4];
  const float* Wv = (const float*)d_in[5];
  const float* bv = (const float*)d_in[6];
  const float* Wo = (const float*)d_in[7];
  const float* bo = (const float*)d_in[8];

  float* out = (float*)d_out;
  float* attSum = out + (size_t)MROWS * DDIM;
  float* attMask = attSum + (size_t)NB * SDIM * SDIM;

  char* ws = (char*)d_ws;
  const size_t bigF = (size_t)MROWS * DDIM * sizeof(float);    // 16.78 MB
  const size_t bigH = (size_t)MROWS * DDIM * sizeof(_Float16); // 8.39 MB
  const size_t wH = (size_t)DDIM * DDIM * sizeof(_Float16);    // 2.10 MB
  _Float16* Qh = (_Float16*)ws;  ws += bigH;
  _Float16* Kh = (_Float16*)ws;  ws += bigH;
  float* merged = (float*)ws;    ws += bigF;
  _Float16* xh = (_Float16*)ws;  ws += bigH;
  _Float16* Wqh = (_Float16*)ws; ws += wH;
  _Float16* Wkh = (_Float16*)ws; ws += wH;
  float* den = (float*)ws;       ws += (size_t)NB * NH * SDIM * sizeof(float);
  float4* ev = (float4*)ws;      ws += (size_t)MAXEV * sizeof(float4);
  int* flags = (int*)ws;         ws += (size_t)MROWS * sizeof(int);
  int* ecnt = (int*)ws;          ws += 16;

  hipMemsetAsync(merged, 0, bigF, stream);
  hipMemsetAsync(flags, 0, (size_t)MROWS * sizeof(int), stream);
  hipMemsetAsync(ecnt, 0, 16, stream);
  hipMemsetAsync(den, 0, (size_t)NB * NH * SDIM * sizeof(float), stream);
  hipMemsetAsync(attMask, 0, (size_t)NB * SDIM * SDIM * sizeof(float), stream);

  dim3 blk(256);
  cvt_f16<<<dim3(6144), blk, 0, stream>>>(x, Wq, Wk, xh, Wqh, Wkh);
  proj_gemm<<<dim3(8, 32, 2), blk, 0, stream>>>(xh, Wqh, Wkh, bq, bk, Qh, Kh);
  attn_denom<<<dim3(32, 32, 2), blk, 0, stream>>>(Qh, Kh, den);
  attn_pass2<<<dim3(32, 32, 2), blk, 0, stream>>>(Qh, Kh, den, attSum,
                                                  attMask, ev, ecnt);
  apply_events<<<dim3(256), dim3(64), 0, stream>>>(ev, ecnt, x, Wv, bv, merged,
                                                   flags);
  out_gemm<<<dim3(16, 64), blk, 0, stream>>>(merged, Wo, bo, out, flags);
}